// Round 1
// baseline (86.097 us; speedup 1.0000x reference)
//
#include <hip/hip_runtime.h>
#include <math.h>

#define B_    256
#define I_    128
#define O_    256
#define D_    33
#define NSUM  100
#define NPROD 10
#define A_SUP 1.5f
#define PI_F  3.14159265358979323846f

// ---------------------------------------------------------------------------
// Prep: transpose W[i][o][d] -> Wt[i][d][o] so that per-(i, d-window) reads in
// the main kernel are contiguous & coalesced across the o dimension.
// One block per i. LDS reads ld[o*33+d]: stride 33 mod 32 == 1 -> conflict-free.
// ---------------------------------------------------------------------------
__global__ __launch_bounds__(256) void transpose_w(const float* __restrict__ W,
                                                   float* __restrict__ Wt) {
    const int i = blockIdx.x;
    __shared__ float ld[O_ * D_];                 // 33 KiB
    const float* src = W + (size_t)i * O_ * D_;
    for (int t = threadIdx.x; t < O_ * D_; t += blockDim.x)
        ld[t] = src[t];
    __syncthreads();
    float* dst = Wt + (size_t)i * D_ * O_;
    for (int t = threadIdx.x; t < D_ * O_; t += blockDim.x) {
        const int d = t >> 8;                     // t / 256
        const int o = t & (O_ - 1);               // t % 256
        dst[t] = ld[o * D_ + d];
    }
}

// ---------------------------------------------------------------------------
// Main: one block per batch row b. 512 threads.
// Phase A: sparse basis (128 i x 4 d window) via Chebyshev cos recurrence.
// Phase B: y[b,o] = sum_i sum_dd basis[i][dd] * Wt[i][d0+dd][o], coalesced.
// ---------------------------------------------------------------------------
template <bool USE_WT>
__global__ __launch_bounds__(512, 2) void kan_main(const float* __restrict__ x,
                                                   const float* __restrict__ W,
                                                   const float* __restrict__ comp,
                                                   const float* __restrict__ cen,
                                                   float* __restrict__ y) {
    const int b   = blockIdx.x;
    const int tid = threadIdx.x;

    __shared__ float sc[NSUM];        // Fourier coefficients c_k
    __shared__ float sx[I_];          // x row
    __shared__ int   sd0[I_];         // window start per i
    __shared__ float sbasis[I_][4];   // sparse basis values
    __shared__ float spart[512];      // final reduction

    // --- Fourier coefficients (input-independent, cheap: ~11 sinf each) ---
    if (tid < NSUM) {
        const float k = (float)(tid + 1);
        const float t = PI_F * k / A_SUP;
        float z0 = 0.5f * t;
        float c  = sinf(z0) / z0;                 // sinc(t/2)^n, n = 1
        float div = 0.5f;
        #pragma unroll
        for (int j = 1; j <= NPROD; ++j) {        // prod_{j=1..10} sinc(t/2^j)
            const float zz = t * div;
            c *= sinf(zz) / zz;
            div *= 0.5f;
        }
        sc[tid] = c;
    }

    // --- per-i window start: active d satisfy |(x - c_d)*16| <= 1.5 ---
    if (tid < I_) {
        const float xv = x[b * I_ + tid];
        sx[tid] = xv;
        const float lo = 16.0f * (xv + 1.0f) - A_SUP;   // d >= lo
        int d0 = (int)ceilf(lo);
        d0 = min(max(d0, 0), D_ - 4);
        sd0[tid] = d0;
    }
    __syncthreads();

    // --- Phase A: 512 series, one per thread: (i, dd) = (tid>>2, tid&3) ---
    {
        const int i  = tid >> 2;
        const int dd = tid & 3;
        const int d  = sd0[i] + dd;
        const float z = (sx[i] - cen[d]) * comp[d];     // same op order as ref
        float s = 0.0f;
        if (fabsf(z) <= A_SUP) {
            const float th   = (PI_F / A_SUP) * z;
            const float c1   = cosf(th);
            float ckm1 = c1, ckm2 = 1.0f;
            s = 0.5f + sc[0] * c1;
            #pragma unroll 4
            for (int k = 2; k <= NSUM; ++k) {
                const float ck = 2.0f * c1 * ckm1 - ckm2;
                s += sc[k - 1] * ck;
                ckm2 = ckm1;
                ckm1 = ck;
            }
            s *= (1.0f / A_SUP);
        }
        sbasis[i][dd] = s;
    }
    __syncthreads();

    // --- Phase B: contraction. thread = (h, o); h splits the i range ---
    const int o = tid & (O_ - 1);
    const int h = tid >> 8;                       // 0 or 1
    float acc = 0.0f;
    const int i_lo = h * (I_ / 2);
    if (USE_WT) {
        #pragma unroll 4
        for (int i = i_lo; i < i_lo + I_ / 2; ++i) {
            const int d0 = sd0[i];
            const float* wp = W + (((size_t)(i * D_ + d0)) << 8) + o;  // Wt[i][d0][o]
            const float b0 = sbasis[i][0], b1 = sbasis[i][1];
            const float b2 = sbasis[i][2], b3 = sbasis[i][3];
            acc += b0 * wp[0]       + b1 * wp[O_]
                 + b2 * wp[2 * O_]  + b3 * wp[3 * O_];
        }
    } else {
        #pragma unroll 4
        for (int i = i_lo; i < i_lo + I_ / 2; ++i) {
            const int d0 = sd0[i];
            const float* wp = W + ((size_t)(i * O_ + o)) * D_ + d0;    // W[i][o][d0]
            acc += sbasis[i][0] * wp[0] + sbasis[i][1] * wp[1]
                 + sbasis[i][2] * wp[2] + sbasis[i][3] * wp[3];
        }
    }
    spart[tid] = acc;
    __syncthreads();
    if (tid < O_)
        y[b * O_ + tid] = spart[tid] + spart[tid + O_];
}

extern "C" void kernel_launch(void* const* d_in, const int* in_sizes, int n_in,
                              void* d_out, int out_size, void* d_ws, size_t ws_size,
                              hipStream_t stream) {
    const float* x    = (const float*)d_in[0];
    const float* W    = (const float*)d_in[1];   // (I, O, D)
    const float* comp = (const float*)d_in[2];   // (D,)
    const float* cen  = (const float*)d_in[3];   // (D,)
    float* y = (float*)d_out;                    // (B, O)

    const size_t wt_bytes = (size_t)I_ * D_ * O_ * sizeof(float);
    if (ws_size >= wt_bytes) {
        float* Wt = (float*)d_ws;
        transpose_w<<<I_, 256, 0, stream>>>(W, Wt);
        kan_main<true><<<B_, 512, 0, stream>>>(x, Wt, comp, cen, y);
    } else {
        kan_main<false><<<B_, 512, 0, stream>>>(x, W, comp, cen, y);
    }
}